// Round 5
// baseline (192.522 us; speedup 1.0000x reference)
//
#include <hip/hip_runtime.h>
#include <hip/hip_bf16.h>
#include <stdint.h>

// SVDHead: scores=softmax(QK^T/sqrt(dk)) over m; corr = scores @ src(3);
// H = (target-mu_t)^T (corr-mu_c); R,t from 3x3 SVD (Kabsch).
// Q=src_embedding [16,2048,512] f32, K=target_embedding, V=src [16,2048,3],
// target [16,2048,3]. Out: R [16,3,3] then t [16,1,3] (192 f32).

#define B_  16
#define N_  2048
#define DK_ 512
#define SCALE 0.044194173824159216f  // 1/sqrt(512)

typedef __bf16 bf16x8 __attribute__((ext_vector_type(8)));
typedef float  f32x16 __attribute__((ext_vector_type(16)));
typedef float  f32x4  __attribute__((ext_vector_type(4)));

union BF8 { bf16x8 v; unsigned u[4]; };

__device__ inline unsigned pkbf(float a, float b) {
  unsigned r;
  asm("v_cvt_pk_bf16_f32 %0, %1, %2" : "=v"(r) : "v"(a), "v"(b));
  return r;
}

// ---------------------------------------------------------------------------
// Kernel 1: attention row-stats. EXACT R1 tile-loop body (verified 157us,
// VGPR=128, no spill): 512 thr = 8 waves x 32 q-rows, stg[8] reg prefetch,
// const-indexed qf (rule #20), row<<4 conflict-free swizzle, 2 barriers/tile.
// Only the decomposition changes vs R1: m-chunk = 512 rows (ms in 0..3),
// NT = 16 tiles -> grid = 16b x 8nb x 4ms = 512 blocks = 2 blocks/CU, so one
// block's barrier/load-wait stalls overlap the other block's MFMA phase.
// ---------------------------------------------------------------------------
__global__ __launch_bounds__(512, 2)
void attn_stats_kernel(const float* __restrict__ Q, const float* __restrict__ K,
                       const float* __restrict__ Vsrc, float* __restrict__ part)
{
  __shared__ __align__(16) unsigned char s_k[32 * 1024];  // 32 m x 512 d bf16, swizzled
  __shared__ __align__(16) float s_srcT[3 * 512];         // srcT[c][m-chunk]

  const int L   = blockIdx.x;
  const int b   = L & 15;              // batch spread across consecutive blocks
  const int rem = L >> 4;              // 0..31
  const int nb  = rem & 7;             // q-block 0..7 (256 rows)
  const int ms  = rem >> 3;            // m-chunk 0..3 (512 rows)

  const int tid  = threadIdx.x;
  const int lane = tid & 63;
  const int wid  = tid >> 6;           // 0..7
  const int row  = lane & 31;
  const int hi   = lane >> 5;

  const int mchunk0 = ms * 512;

  // stage srcT: s_srcT[c][m] = Vsrc[b][mchunk0+m][c]
  {
    const float* vp = Vsrc + ((size_t)b * N_ + mchunk0) * 3;
    for (int idx = tid; idx < 1536; idx += 512) {
      int m = idx / 3, c = idx - 3 * m;
      s_srcT[c * 512 + m] = vp[idx];
    }
  }

  // Q fragments in registers: lane holds Q[qglob][d = t*16 + hi*8 .. +8) bf16
  const int qglob = nb * 256 + wid * 32 + row;
  BF8 qf[32];
  {
    const f32x4* qp = (const f32x4*)(Q + ((size_t)b * N_ + qglob) * DK_);
    #pragma unroll
    for (int t = 0; t < 32; ++t) {
      f32x4 f0 = qp[t * 4 + hi * 2];
      f32x4 f1 = qp[t * 4 + hi * 2 + 1];
      qf[t].u[0] = pkbf(f0[0], f0[1]);
      qf[t].u[1] = pkbf(f0[2], f0[3]);
      qf[t].u[2] = pkbf(f1[0], f1[1]);
      qf[t].u[3] = pkbf(f1[2], f1[3]);
    }
  }

  const f32x4* kg = (const f32x4*)(K + ((size_t)b * N_ + mchunk0) * DK_);

  float lsum = 0.f, a0 = 0.f, a1 = 0.f, a2 = 0.f;

  // prefetch tile 0 (f32x4 index = i*512 + tid, lane-contiguous -> coalesced)
  f32x4 stg[8];
  #pragma unroll
  for (int i = 0; i < 8; ++i) stg[i] = kg[i * 512 + tid];

  const unsigned kread_base = (unsigned)(row * 1024);
  const unsigned kread_xor  = (unsigned)(row << 4);   // 32 slots: conflict-free

  for (int tile = 0; tile < 16; ++tile) {
    __syncthreads();  // prev tile's LDS reads done -> free to overwrite
    // write staged fp32 -> bf16 LDS, swizzled: byte = r*1024 + (col8 ^ (r<<4))
    #pragma unroll
    for (int i = 0; i < 8; ++i) {
      int idx  = i * 512 + tid;        // f32x4 index in 32x512 tile
      int r    = idx >> 7;             // m-row 0..31
      int colb = (idx & 127) * 8;      // byte col (bf16 row is 1024 B)
      unsigned addr = (unsigned)(r * 1024) + ((unsigned)colb ^ ((unsigned)(r << 4)));
      uint2 w2;
      w2.x = pkbf(stg[i][0], stg[i][1]);
      w2.y = pkbf(stg[i][2], stg[i][3]);
      *(uint2*)(s_k + addr) = w2;
    }
    __syncthreads();
    // prefetch next tile (latency hides under MFMA phase)
    if (tile + 1 < 16) {
      const f32x4* kt = kg + (size_t)(tile + 1) * 4096;
      #pragma unroll
      for (int i = 0; i < 8; ++i) stg[i] = kt[i * 512 + tid];
    }
    // scores: 32 MFMA (2 accumulator chains), out[m][q]
    f32x16 sc0, sc1;
    #pragma unroll
    for (int i = 0; i < 16; ++i) { sc0[i] = 0.f; sc1[i] = 0.f; }
    __builtin_amdgcn_s_setprio(1);
    #pragma unroll
    for (int t = 0; t < 32; t += 2) {
      BF8 kf0, kf1;
      kf0.v = *(const bf16x8*)(s_k + kread_base +
                (((unsigned)(t * 32 + hi * 16)) ^ kread_xor));
      sc0 = __builtin_amdgcn_mfma_f32_32x32x16_bf16(kf0.v, qf[t].v, sc0, 0, 0, 0);
      kf1.v = *(const bf16x8*)(s_k + kread_base +
                (((unsigned)((t + 1) * 32 + hi * 16)) ^ kread_xor));
      sc1 = __builtin_amdgcn_mfma_f32_32x32x16_bf16(kf1.v, qf[t + 1].v, sc1, 0, 0, 0);
    }
    __builtin_amdgcn_s_setprio(0);
    // softmax terms (no max subtraction: |s/sqrt(dk)| small) + PV partials.
    // C layout: col=lane&31 (=q), row m = (reg&3) + 8*(reg>>2) + 4*hi.
    // srcT reads are wave-uniform (broadcast, conflict-free).
    #pragma unroll
    for (int j = 0; j < 4; ++j) {
      const int mrun = tile * 32 + j * 8 + hi * 4;
      f32x4 s0 = *(const f32x4*)&s_srcT[mrun];
      f32x4 s1 = *(const f32x4*)&s_srcT[512 + mrun];
      f32x4 s2 = *(const f32x4*)&s_srcT[1024 + mrun];
      #pragma unroll
      for (int i2 = 0; i2 < 4; ++i2) {
        float w = __expf((sc0[j * 4 + i2] + sc1[j * 4 + i2]) * SCALE);
        lsum += w;
        a0 += w * s0[i2];
        a1 += w * s1[i2];
        a2 += w * s2[i2];
      }
    }
  }

  // lanes l and l+32 hold complementary m-subsets of the same q column
  a0   += __shfl_xor(a0, 32);
  a1   += __shfl_xor(a1, 32);
  a2   += __shfl_xor(a2, 32);
  lsum += __shfl_xor(lsum, 32);

  if (hi == 0) {
    f32x4 o; o[0] = a0; o[1] = a1; o[2] = a2; o[3] = lsum;
    *(f32x4*)(part + (((size_t)ms * B_ + b) * N_ + qglob) * 4) = o;
  }
}

// ---------------------------------------------------------------------------
// Kernel 2: per-batch reduction -> [sum_t(3), sum_corr(3), S=sum t*corr^T(9)]
// Sums the 4 ms partial slices per q-row.
// ---------------------------------------------------------------------------
__global__ void reduce_kernel(const float* __restrict__ part,
                              const float* __restrict__ tgt,
                              float* __restrict__ ws2)
{
  const int b = blockIdx.x, tid = threadIdx.x;
  float s[15];
  #pragma unroll
  for (int j = 0; j < 15; ++j) s[j] = 0.f;

  for (int n = tid; n < N_; n += 256) {
    f32x4 p0 = *(const f32x4*)(part + (((size_t)0 * B_ + b) * N_ + n) * 4);
    f32x4 p1 = *(const f32x4*)(part + (((size_t)1 * B_ + b) * N_ + n) * 4);
    f32x4 p2 = *(const f32x4*)(part + (((size_t)2 * B_ + b) * N_ + n) * 4);
    f32x4 p3 = *(const f32x4*)(part + (((size_t)3 * B_ + b) * N_ + n) * 4);
    float l  = p0[3] + p1[3] + p2[3] + p3[3];
    float inv = 1.0f / l;
    float c0 = (p0[0] + p1[0] + p2[0] + p3[0]) * inv;
    float c1 = (p0[1] + p1[1] + p2[1] + p3[1]) * inv;
    float c2 = (p0[2] + p1[2] + p2[2] + p3[2]) * inv;
    const float* tp = tgt + ((size_t)b * N_ + n) * 3;
    float t0 = tp[0], t1 = tp[1], t2 = tp[2];
    s[0] += t0;  s[1] += t1;  s[2] += t2;
    s[3] += c0;  s[4] += c1;  s[5] += c2;
    s[6] += t0 * c0;  s[7]  += t0 * c1;  s[8]  += t0 * c2;
    s[9] += t1 * c0;  s[10] += t1 * c1;  s[11] += t1 * c2;
    s[12] += t2 * c0; s[13] += t2 * c1;  s[14] += t2 * c2;
  }
  #pragma unroll
  for (int j = 0; j < 15; ++j) {
    #pragma unroll
    for (int off = 32; off > 0; off >>= 1) s[j] += __shfl_xor(s[j], off);
  }
  __shared__ float red[4][15];
  int lane = tid & 63, w = tid >> 6;
  if (lane == 0) {
    #pragma unroll
    for (int j = 0; j < 15; ++j) red[w][j] = s[j];
  }
  __syncthreads();
  if (tid < 15)
    ws2[b * 16 + tid] = red[0][tid] + red[1][tid] + red[2][tid] + red[3][tid];
}

// ---------------------------------------------------------------------------
// Kernel 3: 3x3 SVD (double Jacobi on H^T H) + Kabsch R, t. 1 thread/batch.
// R = u1 v1^T + u2 v2^T + det(V) * (u1 x u2) v3^T  (invariant to sign picks)
// ---------------------------------------------------------------------------
__device__ inline void jrot(double A[3][3], double V[3][3], int p, int q) {
  double apq = A[p][q];
  if (fabs(apq) < 1e-300) return;
  double tau = (A[q][q] - A[p][p]) / (2.0 * apq);
  double tt = (tau >= 0.0) ? 1.0 / (tau + sqrt(1.0 + tau * tau))
                           : 1.0 / (tau - sqrt(1.0 + tau * tau));
  double c = 1.0 / sqrt(1.0 + tt * tt), sn = tt * c;
  for (int k = 0; k < 3; ++k) {
    double akp = A[k][p], akq = A[k][q];
    A[k][p] = c * akp - sn * akq;
    A[k][q] = sn * akp + c * akq;
  }
  for (int k = 0; k < 3; ++k) {
    double apk = A[p][k], aqk = A[q][k];
    A[p][k] = c * apk - sn * aqk;
    A[q][k] = sn * apk + c * aqk;
  }
  for (int k = 0; k < 3; ++k) {
    double vkp = V[k][p], vkq = V[k][q];
    V[k][p] = c * vkp - sn * vkq;
    V[k][q] = sn * vkp + c * vkq;
  }
}

__global__ void svd_kernel(const float* __restrict__ ws2, float* __restrict__ out)
{
  const int b = threadIdx.x;
  if (b >= B_) return;
  const float* s = ws2 + b * 16;
  const double invN = 1.0 / (double)N_;
  double stv[3] = {s[0], s[1], s[2]};
  double scv[3] = {s[3], s[4], s[5]};
  double H[3][3];
  for (int c = 0; c < 3; ++c)
    for (int d = 0; d < 3; ++d)
      H[c][d] = (double)s[6 + c * 3 + d] - stv[c] * scv[d] * invN;

  double A[3][3], V[3][3] = {{1,0,0},{0,1,0},{0,0,1}};
  for (int i = 0; i < 3; ++i)
    for (int j = 0; j < 3; ++j) {
      double acc = 0.0;
      for (int c = 0; c < 3; ++c) acc += H[c][i] * H[c][j];
      A[i][j] = acc;
    }
  for (int sw = 0; sw < 15; ++sw) { jrot(A,V,0,1); jrot(A,V,0,2); jrot(A,V,1,2); }

  double e[3] = {A[0][0], A[1][1], A[2][2]};
  double vc[3][3];
  for (int k = 0; k < 3; ++k)
    for (int i = 0; i < 3; ++i) vc[k][i] = V[i][k];
  for (int a2 = 0; a2 < 2; ++a2)
    for (int b2 = 0; b2 < 2 - a2; ++b2)
      if (e[b2] < e[b2 + 1]) {
        double te = e[b2]; e[b2] = e[b2 + 1]; e[b2 + 1] = te;
        for (int i = 0; i < 3; ++i) {
          double tv = vc[b2][i]; vc[b2][i] = vc[b2 + 1][i]; vc[b2 + 1][i] = tv;
        }
      }

  double u1[3], u2[3], u3[3];
  for (int i = 0; i < 3; ++i)
    u1[i] = H[i][0]*vc[0][0] + H[i][1]*vc[0][1] + H[i][2]*vc[0][2];
  double n1 = sqrt(u1[0]*u1[0] + u1[1]*u1[1] + u1[2]*u1[2]);
  n1 = fmax(n1, 1e-300);
  for (int i = 0; i < 3; ++i) u1[i] /= n1;
  for (int i = 0; i < 3; ++i)
    u2[i] = H[i][0]*vc[1][0] + H[i][1]*vc[1][1] + H[i][2]*vc[1][2];
  double d12 = u1[0]*u2[0] + u1[1]*u2[1] + u1[2]*u2[2];
  for (int i = 0; i < 3; ++i) u2[i] -= d12 * u1[i];
  double n2 = sqrt(u2[0]*u2[0] + u2[1]*u2[1] + u2[2]*u2[2]);
  n2 = fmax(n2, 1e-300);
  for (int i = 0; i < 3; ++i) u2[i] /= n2;
  u3[0] = u1[1]*u2[2] - u1[2]*u2[1];
  u3[1] = u1[2]*u2[0] - u1[0]*u2[2];
  u3[2] = u1[0]*u2[1] - u1[1]*u2[0];

  double detV = vc[0][0]*(vc[1][1]*vc[2][2] - vc[1][2]*vc[2][1])
              - vc[0][1]*(vc[1][0]*vc[2][2] - vc[1][2]*vc[2][0])
              + vc[0][2]*(vc[1][0]*vc[2][1] - vc[1][1]*vc[2][0]);

  double R[3][3];
  for (int i = 0; i < 3; ++i)
    for (int j = 0; j < 3; ++j)
      R[i][j] = u1[i]*vc[0][j] + u2[i]*vc[1][j] + detV * u3[i]*vc[2][j];

  for (int i = 0; i < 3; ++i)
    for (int j = 0; j < 3; ++j)
      out[b * 9 + i * 3 + j] = (float)R[i][j];

  double muc[3] = {scv[0]*invN, scv[1]*invN, scv[2]*invN};
  for (int i = 0; i < 3; ++i) {
    double ti = stv[i]*invN - (R[i][0]*muc[0] + R[i][1]*muc[1] + R[i][2]*muc[2]);
    out[B_ * 9 + b * 3 + i] = (float)ti;
  }
}

// ---------------------------------------------------------------------------
extern "C" void kernel_launch(void* const* d_in, const int* in_sizes, int n_in,
                              void* d_out, int out_size, void* d_ws, size_t ws_size,
                              hipStream_t stream)
{
  const float* srcE = (const float*)d_in[0];  // Q
  const float* tgtE = (const float*)d_in[1];  // K
  const float* srcP = (const float*)d_in[2];  // V (3-wide)
  const float* tgtP = (const float*)d_in[3];  // target points
  float* out  = (float*)d_out;
  float* part = (float*)d_ws;                         // 4*16*2048*4 floats = 2 MB
  float* ws2  = part + (size_t)4 * B_ * N_ * 4;       // 16*16 floats

  attn_stats_kernel<<<dim3(512), dim3(512), 0, stream>>>(srcE, tgtE, srcP, part);
  reduce_kernel<<<dim3(B_), dim3(256), 0, stream>>>(part, tgtP, ws2);
  svd_kernel<<<dim3(1), dim3(64), 0, stream>>>(ws2, out);
}

// Round 6
// 131.765 us; speedup vs baseline: 1.4611x; 1.4611x over previous
//
#include <hip/hip_runtime.h>
#include <hip/hip_bf16.h>
#include <stdint.h>

// SVDHead: scores=softmax(QK^T/sqrt(dk)) over m; corr = scores @ src(3);
// H = (target-mu_t)^T (corr-mu_c); R,t from 3x3 SVD (Kabsch).
// Q=src_embedding [16,2048,512] f32, K=target_embedding, V=src [16,2048,3],
// target [16,2048,3]. Out: R [16,3,3] then t [16,1,3] (192 f32).

#define B_  16
#define N_  2048
#define DK_ 512
#define SCALE 0.044194173824159216f  // 1/sqrt(512)

typedef __bf16 bf16x8 __attribute__((ext_vector_type(8)));
typedef float  f32x16 __attribute__((ext_vector_type(16)));
typedef float  f32x4  __attribute__((ext_vector_type(4)));

union BF8 { bf16x8 v; unsigned u[4]; };

__device__ inline unsigned pkbf(float a, float b) {
  unsigned r;
  asm("v_cvt_pk_bf16_f32 %0, %1, %2" : "=v"(r) : "v"(a), "v"(b));
  return r;
}

// global(AS1) -> LDS(AS3) direct 16B DMA; dest = wave-uniform base + lane*16
__device__ inline void gl_lds16(const void* g, void* l) {
  __builtin_amdgcn_global_load_lds(
      (const __attribute__((address_space(1))) unsigned int*)g,
      (__attribute__((address_space(3))) unsigned int*)l, 16, 0, 0);
}

// ---------------------------------------------------------------------------
// Kernel 0 (prepass): K f32 -> bf16, 8 elems/thread/iter.
// ---------------------------------------------------------------------------
__global__ __launch_bounds__(256)
void cvt_k_kernel(const float* __restrict__ in, uint4* __restrict__ out)
{
  const size_t total = (size_t)B_ * N_ * DK_ / 8;  // 2,097,152
  for (size_t i = (size_t)blockIdx.x * 256 + threadIdx.x; i < total;
       i += (size_t)gridDim.x * 256) {
    f32x4 a = ((const f32x4*)in)[2 * i];
    f32x4 c = ((const f32x4*)in)[2 * i + 1];
    uint4 w;
    w.x = pkbf(a[0], a[1]);
    w.y = pkbf(a[2], a[3]);
    w.z = pkbf(c[0], c[1]);
    w.w = pkbf(c[2], c[3]);
    out[i] = w;
  }
}

// ---------------------------------------------------------------------------
// Kernel 1: attention row-stats. R1 mapping + MFMA body (verified), but K is
// pre-converted bf16 and staged via global_load_lds (16B) into DOUBLE-
// buffered LDS -> no reg staging, no cvt in hot loop, ONE barrier per tile.
// Swizzle preserved by pre-swizzled GLOBAL source (m173 pattern):
//   wave loads row r: lane i fetches row-bytes 16*(i^r), LDS dest linear
//   r*1024 + i*16  =>  LDS[r*1024 + x] = K[r][x ^ (r<<4)]  (same as R1).
// Read side unchanged from R1: byte = row*1024 + (col ^ (row<<4)), conflict-
// free (49K total conflicts measured).
// ---------------------------------------------------------------------------
__global__ __launch_bounds__(512, 2)
void attn_stats_kernel(const float* __restrict__ Q,
                       const unsigned char* __restrict__ Kbf,
                       const float* __restrict__ Vsrc, float* __restrict__ part)
{
  __shared__ __align__(16) unsigned char s_k[2][32 * 1024]; // dbuf 32m x 1024B
  __shared__ __align__(16) float s_srcT[3 * 1024];          // srcT[c][m]

  const int L   = blockIdx.x;
  const int xcd = L & 7;               // round-robin XCD mapping
  const int kk  = L >> 3;
  const int b   = xcd + 8 * (kk & 1);  // 2 batches per XCD
  const int ms  = (kk >> 1) & 1;       // m-chunk 0/1 (1024 rows)
  const int nb  = kk >> 2;             // q-block 0..7 (256 rows)

  const int tid  = threadIdx.x;
  const int lane = tid & 63;
  const int wid  = tid >> 6;           // 0..7
  const int row  = lane & 31;
  const int hi   = lane >> 5;

  const int mchunk0 = ms * 1024;

  // stage srcT: s_srcT[c][m] = Vsrc[b][mchunk0+m][c]
  {
    const float* vp = Vsrc + ((size_t)b * N_ + mchunk0) * 3;
    for (int idx = tid; idx < 3072; idx += 512) {
      int m = idx / 3, c = idx - 3 * m;
      s_srcT[c * 1024 + m] = vp[idx];
    }
  }

  // Q fragments in registers: lane holds Q[qglob][d = t*16 + hi*8 .. +8) bf16
  // qf indexed ONLY by compile-time constants (rule #20).
  const int qglob = nb * 256 + wid * 32 + row;
  BF8 qf[32];
  {
    const f32x4* qp = (const f32x4*)(Q + ((size_t)b * N_ + qglob) * DK_);
    #pragma unroll
    for (int t = 0; t < 32; ++t) {
      f32x4 f0 = qp[t * 4 + hi * 2];
      f32x4 f1 = qp[t * 4 + hi * 2 + 1];
      qf[t].u[0] = pkbf(f0[0], f0[1]);
      qf[t].u[1] = pkbf(f0[2], f0[3]);
      qf[t].u[2] = pkbf(f1[0], f1[1]);
      qf[t].u[3] = pkbf(f1[2], f1[3]);
    }
  }

  // bf16 K base for this (b, ms); row byte-stride 1024
  const unsigned char* kbase = Kbf + ((size_t)b * N_ + mchunk0) * (DK_ * 2);

  // wave wid stages rows r = wid*4+j of tile t into buf bb; source lane-
  // permuted by ^r so linear LDS dest yields the swizzled layout.
  #define STAGE(bb, t)                                                       \
    { _Pragma("unroll")                                                      \
      for (int j = 0; j < 4; ++j) {                                          \
        const int r_ = wid * 4 + j;                                          \
        gl_lds16(kbase + (((size_t)(t) * 32 + r_) << 10)                     \
                       + (unsigned)((lane ^ r_) << 4),                       \
                 &s_k[bb][r_ << 10]);                                        \
      } }

  float lsum = 0.f, a0 = 0.f, a1 = 0.f, a2 = 0.f;

  const unsigned kread_base = (unsigned)(row * 1024);
  const unsigned kread_xor  = (unsigned)(row << 4);   // 32 slots: conflict-free

  // prologue: tile 0 -> buf0 (syncthreads drains vmcnt before barrier)
  STAGE(0, 0)
  __syncthreads();

  for (int tile = 0; tile < 32; ++tile) {
    const int cur = tile & 1;
    if (tile + 1 < 32) STAGE(cur ^ 1, tile + 1)   // in flight across MFMA

    const unsigned char* bp = &s_k[cur][0];
    f32x16 sc0, sc1;
    #pragma unroll
    for (int i = 0; i < 16; ++i) { sc0[i] = 0.f; sc1[i] = 0.f; }
    __builtin_amdgcn_s_setprio(1);
    #pragma unroll
    for (int t = 0; t < 32; t += 2) {
      BF8 kf0, kf1;
      kf0.v = *(const bf16x8*)(bp + kread_base +
                (((unsigned)(t * 32 + hi * 16)) ^ kread_xor));
      sc0 = __builtin_amdgcn_mfma_f32_32x32x16_bf16(kf0.v, qf[t].v, sc0, 0, 0, 0);
      kf1.v = *(const bf16x8*)(bp + kread_base +
                (((unsigned)((t + 1) * 32 + hi * 16)) ^ kread_xor));
      sc1 = __builtin_amdgcn_mfma_f32_32x32x16_bf16(kf1.v, qf[t + 1].v, sc1, 0, 0, 0);
    }
    __builtin_amdgcn_s_setprio(0);

    // softmax terms (no max subtraction: |s/sqrt(dk)| small) + PV partials.
    // C layout: col=lane&31 (=q), row m = (reg&3) + 8*(reg>>2) + 4*hi.
    #pragma unroll
    for (int j = 0; j < 4; ++j) {
      const int mrun = tile * 32 + j * 8 + hi * 4;
      f32x4 s0 = *(const f32x4*)&s_srcT[mrun];
      f32x4 s1 = *(const f32x4*)&s_srcT[1024 + mrun];
      f32x4 s2 = *(const f32x4*)&s_srcT[2048 + mrun];
      #pragma unroll
      for (int i2 = 0; i2 < 4; ++i2) {
        float w = __expf((sc0[j * 4 + i2] + sc1[j * 4 + i2]) * SCALE);
        lsum += w;
        a0 += w * s0[i2];
        a1 += w * s1[i2];
        a2 += w * s2[i2];
      }
    }

    __syncthreads();  // buf[cur] reads done; buf[cur^1] loads landed
  }
  #undef STAGE

  // lanes l and l+32 hold complementary m-subsets of the same q column
  a0   += __shfl_xor(a0, 32);
  a1   += __shfl_xor(a1, 32);
  a2   += __shfl_xor(a2, 32);
  lsum += __shfl_xor(lsum, 32);

  if (hi == 0) {
    f32x4 o; o[0] = a0; o[1] = a1; o[2] = a2; o[3] = lsum;
    *(f32x4*)(part + (((size_t)ms * B_ + b) * N_ + qglob) * 4) = o;
  }
}

// ---------------------------------------------------------------------------
// Fallback (exact R1 winner): f32 K with reg staging, used if ws too small.
// ---------------------------------------------------------------------------
__global__ __launch_bounds__(512, 2)
void attn_stats_f32_kernel(const float* __restrict__ Q, const float* __restrict__ K,
                           const float* __restrict__ Vsrc, float* __restrict__ part)
{
  __shared__ __align__(16) unsigned char s_k[32 * 1024];
  __shared__ __align__(16) float s_srcT[3 * 1024];

  const int L   = blockIdx.x;
  const int xcd = L & 7;
  const int kk  = L >> 3;
  const int b   = xcd + 8 * (kk & 1);
  const int ms  = (kk >> 1) & 1;
  const int nb  = kk >> 2;

  const int tid  = threadIdx.x;
  const int lane = tid & 63;
  const int wid  = tid >> 6;
  const int row  = lane & 31;
  const int hi   = lane >> 5;

  const int mchunk0 = ms * 1024;

  {
    const float* vp = Vsrc + ((size_t)b * N_ + mchunk0) * 3;
    for (int idx = tid; idx < 3072; idx += 512) {
      int m = idx / 3, c = idx - 3 * m;
      s_srcT[c * 1024 + m] = vp[idx];
    }
  }

  const int qglob = nb * 256 + wid * 32 + row;
  BF8 qf[32];
  {
    const f32x4* qp = (const f32x4*)(Q + ((size_t)b * N_ + qglob) * DK_);
    #pragma unroll
    for (int t = 0; t < 32; ++t) {
      f32x4 f0 = qp[t * 4 + hi * 2];
      f32x4 f1 = qp[t * 4 + hi * 2 + 1];
      qf[t].u[0] = pkbf(f0[0], f0[1]);
      qf[t].u[1] = pkbf(f0[2], f0[3]);
      qf[t].u[2] = pkbf(f1[0], f1[1]);
      qf[t].u[3] = pkbf(f1[2], f1[3]);
    }
  }

  const f32x4* kg = (const f32x4*)(K + ((size_t)b * N_ + mchunk0) * DK_);

  float lsum = 0.f, a0 = 0.f, a1 = 0.f, a2 = 0.f;

  f32x4 stg[8];
  #pragma unroll
  for (int i = 0; i < 8; ++i) stg[i] = kg[i * 512 + tid];

  const unsigned kread_base = (unsigned)(row * 1024);
  const unsigned kread_xor  = (unsigned)(row << 4);

  for (int tile = 0; tile < 32; ++tile) {
    __syncthreads();
    #pragma unroll
    for (int i = 0; i < 8; ++i) {
      int idx  = i * 512 + tid;
      int r    = idx >> 7;
      int colb = (idx & 127) * 8;
      unsigned addr = (unsigned)(r * 1024) + ((unsigned)colb ^ ((unsigned)(r << 4)));
      uint2 w2;
      w2.x = pkbf(stg[i][0], stg[i][1]);
      w2.y = pkbf(stg[i][2], stg[i][3]);
      *(uint2*)(s_k + addr) = w2;
    }
    __syncthreads();
    if (tile + 1 < 32) {
      const f32x4* kt = kg + (size_t)(tile + 1) * 4096;
      #pragma unroll
      for (int i = 0; i < 8; ++i) stg[i] = kt[i * 512 + tid];
    }
    f32x16 sc0, sc1;
    #pragma unroll
    for (int i = 0; i < 16; ++i) { sc0[i] = 0.f; sc1[i] = 0.f; }
    __builtin_amdgcn_s_setprio(1);
    #pragma unroll
    for (int t = 0; t < 32; t += 2) {
      BF8 kf0, kf1;
      kf0.v = *(const bf16x8*)(s_k + kread_base +
                (((unsigned)(t * 32 + hi * 16)) ^ kread_xor));
      sc0 = __builtin_amdgcn_mfma_f32_32x32x16_bf16(kf0.v, qf[t].v, sc0, 0, 0, 0);
      kf1.v = *(const bf16x8*)(s_k + kread_base +
                (((unsigned)((t + 1) * 32 + hi * 16)) ^ kread_xor));
      sc1 = __builtin_amdgcn_mfma_f32_32x32x16_bf16(kf1.v, qf[t + 1].v, sc1, 0, 0, 0);
    }
    __builtin_amdgcn_s_setprio(0);
    #pragma unroll
    for (int j = 0; j < 4; ++j) {
      const int mrun = tile * 32 + j * 8 + hi * 4;
      f32x4 s0 = *(const f32x4*)&s_srcT[mrun];
      f32x4 s1 = *(const f32x4*)&s_srcT[1024 + mrun];
      f32x4 s2 = *(const f32x4*)&s_srcT[2048 + mrun];
      #pragma unroll
      for (int i2 = 0; i2 < 4; ++i2) {
        float w = __expf((sc0[j * 4 + i2] + sc1[j * 4 + i2]) * SCALE);
        lsum += w;
        a0 += w * s0[i2];
        a1 += w * s1[i2];
        a2 += w * s2[i2];
      }
    }
  }

  a0   += __shfl_xor(a0, 32);
  a1   += __shfl_xor(a1, 32);
  a2   += __shfl_xor(a2, 32);
  lsum += __shfl_xor(lsum, 32);

  if (hi == 0) {
    f32x4 o; o[0] = a0; o[1] = a1; o[2] = a2; o[3] = lsum;
    *(f32x4*)(part + (((size_t)ms * B_ + b) * N_ + qglob) * 4) = o;
  }
}

// ---------------------------------------------------------------------------
// Kernel 2: per-batch reduction -> [sum_t(3), sum_corr(3), S=sum t*corr^T(9)]
// ---------------------------------------------------------------------------
__global__ void reduce_kernel(const float* __restrict__ part,
                              const float* __restrict__ tgt,
                              float* __restrict__ ws2)
{
  const int b = blockIdx.x, tid = threadIdx.x;
  float s[15];
  #pragma unroll
  for (int j = 0; j < 15; ++j) s[j] = 0.f;

  for (int n = tid; n < N_; n += 256) {
    f32x4 p0 = *(const f32x4*)(part + (((size_t)0 * B_ + b) * N_ + n) * 4);
    f32x4 p1 = *(const f32x4*)(part + (((size_t)1 * B_ + b) * N_ + n) * 4);
    float inv = 1.0f / (p0[3] + p1[3]);
    float c0 = (p0[0] + p1[0]) * inv;
    float c1 = (p0[1] + p1[1]) * inv;
    float c2 = (p0[2] + p1[2]) * inv;
    const float* tp = tgt + ((size_t)b * N_ + n) * 3;
    float t0 = tp[0], t1 = tp[1], t2 = tp[2];
    s[0] += t0;  s[1] += t1;  s[2] += t2;
    s[3] += c0;  s[4] += c1;  s[5] += c2;
    s[6] += t0 * c0;  s[7]  += t0 * c1;  s[8]  += t0 * c2;
    s[9] += t1 * c0;  s[10] += t1 * c1;  s[11] += t1 * c2;
    s[12] += t2 * c0; s[13] += t2 * c1;  s[14] += t2 * c2;
  }
  #pragma unroll
  for (int j = 0; j < 15; ++j) {
    #pragma unroll
    for (int off = 32; off > 0; off >>= 1) s[j] += __shfl_xor(s[j], off);
  }
  __shared__ float red[4][15];
  int lane = tid & 63, w = tid >> 6;
  if (lane == 0) {
    #pragma unroll
    for (int j = 0; j < 15; ++j) red[w][j] = s[j];
  }
  __syncthreads();
  if (tid < 15)
    ws2[b * 16 + tid] = red[0][tid] + red[1][tid] + red[2][tid] + red[3][tid];
}

// ---------------------------------------------------------------------------
// Kernel 3: 3x3 SVD (double Jacobi on H^T H) + Kabsch R, t. 1 thread/batch.
// ---------------------------------------------------------------------------
__device__ inline void jrot(double A[3][3], double V[3][3], int p, int q) {
  double apq = A[p][q];
  if (fabs(apq) < 1e-300) return;
  double tau = (A[q][q] - A[p][p]) / (2.0 * apq);
  double tt = (tau >= 0.0) ? 1.0 / (tau + sqrt(1.0 + tau * tau))
                           : 1.0 / (tau - sqrt(1.0 + tau * tau));
  double c = 1.0 / sqrt(1.0 + tt * tt), sn = tt * c;
  for (int k = 0; k < 3; ++k) {
    double akp = A[k][p], akq = A[k][q];
    A[k][p] = c * akp - sn * akq;
    A[k][q] = sn * akp + c * akq;
  }
  for (int k = 0; k < 3; ++k) {
    double apk = A[p][k], aqk = A[q][k];
    A[p][k] = c * apk - sn * aqk;
    A[q][k] = sn * apk + c * aqk;
  }
  for (int k = 0; k < 3; ++k) {
    double vkp = V[k][p], vkq = V[k][q];
    V[k][p] = c * vkp - sn * vkq;
    V[k][q] = sn * vkp + c * vkq;
  }
}

__global__ void svd_kernel(const float* __restrict__ ws2, float* __restrict__ out)
{
  const int b = threadIdx.x;
  if (b >= B_) return;
  const float* s = ws2 + b * 16;
  const double invN = 1.0 / (double)N_;
  double stv[3] = {s[0], s[1], s[2]};
  double scv[3] = {s[3], s[4], s[5]};
  double H[3][3];
  for (int c = 0; c < 3; ++c)
    for (int d = 0; d < 3; ++d)
      H[c][d] = (double)s[6 + c * 3 + d] - stv[c] * scv[d] * invN;

  double A[3][3], V[3][3] = {{1,0,0},{0,1,0},{0,0,1}};
  for (int i = 0; i < 3; ++i)
    for (int j = 0; j < 3; ++j) {
      double acc = 0.0;
      for (int c = 0; c < 3; ++c) acc += H[c][i] * H[c][j];
      A[i][j] = acc;
    }
  for (int sw = 0; sw < 15; ++sw) { jrot(A,V,0,1); jrot(A,V,0,2); jrot(A,V,1,2); }

  double e[3] = {A[0][0], A[1][1], A[2][2]};
  double vc[3][3];
  for (int k = 0; k < 3; ++k)
    for (int i = 0; i < 3; ++i) vc[k][i] = V[i][k];
  for (int a2 = 0; a2 < 2; ++a2)
    for (int b2 = 0; b2 < 2 - a2; ++b2)
      if (e[b2] < e[b2 + 1]) {
        double te = e[b2]; e[b2] = e[b2 + 1]; e[b2 + 1] = te;
        for (int i = 0; i < 3; ++i) {
          double tv = vc[b2][i]; vc[b2][i] = vc[b2 + 1][i]; vc[b2 + 1][i] = tv;
        }
      }

  double u1[3], u2[3], u3[3];
  for (int i = 0; i < 3; ++i)
    u1[i] = H[i][0]*vc[0][0] + H[i][1]*vc[0][1] + H[i][2]*vc[0][2];
  double n1 = sqrt(u1[0]*u1[0] + u1[1]*u1[1] + u1[2]*u1[2]);
  n1 = fmax(n1, 1e-300);
  for (int i = 0; i < 3; ++i) u1[i] /= n1;
  for (int i = 0; i < 3; ++i)
    u2[i] = H[i][0]*vc[1][0] + H[i][1]*vc[1][1] + H[i][2]*vc[1][2];
  double d12 = u1[0]*u2[0] + u1[1]*u2[1] + u1[2]*u2[2];
  for (int i = 0; i < 3; ++i) u2[i] -= d12 * u1[i];
  double n2 = sqrt(u2[0]*u2[0] + u2[1]*u2[1] + u2[2]*u2[2]);
  n2 = fmax(n2, 1e-300);
  for (int i = 0; i < 3; ++i) u2[i] /= n2;
  u3[0] = u1[1]*u2[2] - u1[2]*u2[1];
  u3[1] = u1[2]*u2[0] - u1[0]*u2[2];
  u3[2] = u1[0]*u2[1] - u1[1]*u2[0];

  double detV = vc[0][0]*(vc[1][1]*vc[2][2] - vc[1][2]*vc[2][1])
              - vc[0][1]*(vc[1][0]*vc[2][2] - vc[1][2]*vc[2][0])
              + vc[0][2]*(vc[1][0]*vc[2][1] - vc[1][1]*vc[2][0]);

  double R[3][3];
  for (int i = 0; i < 3; ++i)
    for (int j = 0; j < 3; ++j)
      R[i][j] = u1[i]*vc[0][j] + u2[i]*vc[1][j] + detV * u3[i]*vc[2][j];

  for (int i = 0; i < 3; ++i)
    for (int j = 0; j < 3; ++j)
      out[b * 9 + i * 3 + j] = (float)R[i][j];

  double muc[3] = {scv[0]*invN, scv[1]*invN, scv[2]*invN};
  for (int i = 0; i < 3; ++i) {
    double ti = stv[i]*invN - (R[i][0]*muc[0] + R[i][1]*muc[1] + R[i][2]*muc[2]);
    out[B_ * 9 + b * 3 + i] = (float)ti;
  }
}

// ---------------------------------------------------------------------------
extern "C" void kernel_launch(void* const* d_in, const int* in_sizes, int n_in,
                              void* d_out, int out_size, void* d_ws, size_t ws_size,
                              hipStream_t stream)
{
  const float* srcE = (const float*)d_in[0];  // Q
  const float* tgtE = (const float*)d_in[1];  // K
  const float* srcP = (const float*)d_in[2];  // V (3-wide)
  const float* tgtP = (const float*)d_in[3];  // target points
  float* out = (float*)d_out;

  const size_t kbf_bytes   = (size_t)B_ * N_ * DK_ * 2;   // 32 MB bf16 K
  const size_t part_floats = (size_t)2 * B_ * N_ * 4;     // 1 MB partials

  if (ws_size >= kbf_bytes + part_floats * 4 + 1024) {
    unsigned char* kbf = (unsigned char*)d_ws;
    float* part = (float*)(kbf + kbf_bytes);
    float* ws2  = part + part_floats;
    cvt_k_kernel<<<dim3(2048), dim3(256), 0, stream>>>(tgtE, (uint4*)kbf);
    attn_stats_kernel<<<dim3(256), dim3(512), 0, stream>>>(srcE, kbf, srcP, part);
    reduce_kernel<<<dim3(B_), dim3(256), 0, stream>>>(part, tgtP, ws2);
    svd_kernel<<<dim3(1), dim3(64), 0, stream>>>(ws2, out);
  } else {
    float* part = (float*)d_ws;
    float* ws2  = part + part_floats;
    attn_stats_f32_kernel<<<dim3(256), dim3(512), 0, stream>>>(srcE, tgtE, srcP, part);
    reduce_kernel<<<dim3(B_), dim3(256), 0, stream>>>(part, tgtP, ws2);
    svd_kernel<<<dim3(1), dim3(64), 0, stream>>>(ws2, out);
  }
}